// Round 7
// baseline (224.057 us; speedup 1.0000x reference)
//
#include <hip/hip_runtime.h>
#include <hip/hip_bf16.h>
#include <stdint.h>

#define FEATURES 256
#define SYMBOLS  1024
#define NPIX     65536        // 16*64*64
#define M_TILE   128          // per block, processed as 2 pipelined halves of 64 rows
#define THREADS  512          // 8 waves: wm = wave>>2 (32-row band), wn = wave&3 (32-sym quarter)
#define A_BYTES  16384        // A image: 64 rows x 256 B fp8, swizzled; rebuilt per half
#define TILE_BYTES 16384      // B tile: 128 syms x 128 feats fp8, pre-swizzled DMA image
#define NBUFS    3            // 3-deep B rotation: steady vmcnt(2), 2-step DMA lead
#define EXTRA_BYTES 5632      // mslot[256](1K) + codes[64](256B) + sspart(32B) + wlds[1024](4K)
#define SMEM_BYTES (A_BYTES + NBUFS * TILE_BYTES + EXTRA_BYTES)   // 69.5 KB -> 2 blocks/CU

typedef float f32x4  __attribute__((ext_vector_type(4)));
typedef float f32x16 __attribute__((ext_vector_type(16)));

// async global->LDS DMA, 16 B per lane; LDS dest = uniform base + lane*16
__device__ __forceinline__ void gld_lds16(const void* g, void* l) {
    __builtin_amdgcn_global_load_lds(
        (const __attribute__((address_space(1))) unsigned int*)g,
        (__attribute__((address_space(3))) unsigned int*)l, 16, 0, 0);
}

// pack 4 fp32 -> 4 fp8 e4m3 (OCP), byte j = element j   [validated: absmax 1.95e-3]
__device__ __forceinline__ uint32_t pack_fp8x4(float a, float b, float c, float d) {
    uint32_t u = 0;
    u = __builtin_amdgcn_cvt_pk_fp8_f32(a, b, u, false);
    u = __builtin_amdgcn_cvt_pk_fp8_f32(c, d, u, true);
    return u;
}

// ---- prep: fp8 DMA-image codebook (x256 scale keeps e4m3 normal), wnorm+1 bias, dev=0 ----
// Tile tt=nc*2+kt: syms [nc*128,+128) x feats [kt*128,+128). Row n = 128 B = 16 8-B
// units; unit u stored at phys u^(n&15).
__global__ __launch_bounds__(64) void vq_prep(const float* __restrict__ W,
                                              char* __restrict__ Wt,
                                              float* __restrict__ wnorm,
                                              float* __restrict__ devslot) {
    int s = blockIdx.x;
    int lane = threadIdx.x;
    int n  = s & 127;
    int nc = s >> 7;
    f32x4 v = ((const f32x4*)(W + (size_t)s * FEATURES))[lane];
    float ss = v[0]*v[0] + v[1]*v[1] + v[2]*v[2] + v[3]*v[3];
    #pragma unroll
    for (int off = 32; off > 0; off >>= 1) ss += __shfl_xor(ss, off);
    if (lane == 0) wnorm[s] = ss + 1.0f;          // +1 bias: keys strictly positive
    if (s == 0 && lane == 0) *devslot = 0.f;

    if (lane < 32) {
        int kt = lane >> 4;
        int u  = lane & 15;
        const float* src = W + (size_t)s * FEATURES + kt * 128 + (u >> 1) * 16 + (u & 1) * 8;
        uint32_t a = pack_fp8x4(256.f*src[0], 256.f*src[1], 256.f*src[2], 256.f*src[3]);
        uint32_t b = pack_fp8x4(256.f*src[4], 256.f*src[5], 256.f*src[6], 256.f*src[7]);
        uint2 w2 = {a, b};
        *(uint2*)(Wt + (size_t)(nc * 2 + kt) * TILE_BYTES + n * 128 + ((u ^ (n & 15)) * 8)) = w2;
    }
}

// ---- main: 2 pipelined 64-row halves per block. Step S (0..31) computes tile S&15 from
// buf S%3. prefetch at step S loads tile (S+3)&15 into buf S%3 (just vacated), AFTER the
// barrier. Steady-state wait before the barrier: vmcnt(2) (only pf@S-1 newer than the
// needed pf@S-2). x(h1) loaded in two 4-load bursts (steps 0,6) + packed one iteration
// per step (2-step latency gap); gather(h0) [16 vmem ops] issued between the K-loops so
// its stores drain under K(h1) -> W table: h0 {63,63,6,2,2,2,2,6,6,2,2,2,2,2,2,2+lgkm},
// h1 {18,18,2,...,2,0,63}. All counts from per-wave FIFO order (2 ops/pf, 1/chunk-load).
__global__ __launch_bounds__(THREADS)
__attribute__((amdgpu_waves_per_eu(4, 4)))   // pin 4 waves/EU: reg budget 128, 2 blocks/CU
void vq_main(
        const float*  __restrict__ x,
        const float*  __restrict__ W,
        const char*   __restrict__ Wt,
        const float*  __restrict__ wnorm,
        float*        __restrict__ out,
        float*        __restrict__ devslot) {
    extern __shared__ char smem[];
    const int t    = threadIdx.x;
    const int lane = t & 63;
    const int wave = t >> 6;             // 0..7
    const int l32  = lane & 31;
    const int half = lane >> 5;          // k-half within a 16-K step
    const int wm   = wave >> 2;          // 0..1: 32-pixel-row band within the 64-row half
    const int wn   = wave & 3;           // 0..3: 32-symbol quarter of the 128-sym tile
    const int m0   = blockIdx.x * M_TILE;
    const float scale = 1.25f / ((float)NPIX * (float)FEATURES);

    char* const bufs = smem + A_BYTES;
    uint32_t* mslot = (uint32_t*)(smem + A_BYTES + NBUFS * TILE_BYTES);      // [4][64]
    int*      codes = (int*)((char*)mslot + 1024);                           // [64]
    float*    sspart = (float*)((char*)mslot + 1280);                        // [8]
    float*    wlds  = (float*)((char*)mslot + 1536);                         // [1024]

    auto prefetch = [&](int tile, int buf) { // 2 DMA ops/wave, 16 x 1 KB total
        const char* g = Wt + (size_t)tile * TILE_BYTES;
        char* dst = bufs + buf * TILE_BYTES;
        #pragma unroll
        for (int j = 0; j < 2; ++j) {
            int i = wave * 2 + j;
            gld_lds16(g + i * 1024 + lane * 16, dst + i * 1024);
        }
    };

    // pack one 8-f32x4-per-thread stage iteration into the A image
    // (row r = 256 B = 32 8-B units, phys unit = u^(r&31)); returns |v|^2
    auto pack_one = [&](int i, f32x4 v) -> float {
        int idx = i * THREADS + t;       // 4096 f32x4 over 64 rows
        int row = idx >> 6;              // wave-uniform
        int k4  = idx & 63;
        uint32_t pk = pack_fp8x4(v[0], v[1], v[2], v[3]);
        int u = k4 >> 1;
        *(uint32_t*)(smem + row * 256 + ((u ^ (row & 31)) * 8) + (k4 & 1) * 4) = pk;
        return v[0]*v[0] + v[1]*v[1] + v[2]*v[2] + v[3]*v[3];
    };

    prefetch(0, 0); prefetch(1, 1); prefetch(2, 2);   // fly under the stage-h0 loads

    const f32x4* xb0 = (const f32x4*)(x + (size_t)m0 * FEATURES);
    const f32x4* xb1 = (const f32x4*)(x + (size_t)(m0 + 64) * FEATURES);
    float ssacc = 0.f;
    {   // ---- stage h0: 8 f32x4/thread, deep-issued ----
        f32x4 xh[8];
        #pragma unroll
        for (int i = 0; i < 8; ++i) xh[i] = xb0[i * THREADS + t];
        wlds[t] = wnorm[t];
        wlds[t + 512] = wnorm[t + 512];
        #pragma unroll
        for (int i = 0; i < 8; ++i) ssacc += pack_one(i, xh[i]);
    }
    __syncthreads();                     // full drain: A(h0) + bufs 0..2 + wlds visible

    long af[16];
    auto extract_af = [&]() {            // af[s] = 8 fp8 of row (wm*32+l32), kstep s
        int r = wm * 32 + l32;
        #pragma unroll
        for (int s = 0; s < 16; ++s)
            af[s] = *(const long*)(smem + r * 256 + (((s * 2 + half) ^ l32) * 8));
    };
    extract_af();

    uint32_t best[16];
    #pragma unroll
    for (int j = 0; j < 16; ++j) best[j] = 0xFFFFFFFFu;
    const int n0 = wn * 32 + l32;        // tile-local B row for this lane
    float bvacc = 0.f;
    f32x4 xc[4];                         // h1 staging burst (transient, 16 regs)

    auto epi = [&](int nc, const f32x16& acc) {
        // score = (1 + wnorm) - (2/256)*acc > 0 -> float bits monotone as uint
        int nb0 = nc * 128 + wn * 32 + l32;
        float w0 = wlds[nb0 & 1023];
        #pragma unroll
        for (int r = 0; r < 16; ++r) {
            float v0 = __builtin_fmaf(-0.0078125f, acc[r], w0);
            uint32_t k0 = (__float_as_uint(v0) & 0xFFFFFC00u) | (uint32_t)nb0;
            if (k0 < best[r]) best[r] = k0;
        }
    };

    auto merge_half = [&]() {            // argmin across lanes + 4 wn quarters -> codes
        #pragma unroll
        for (int r = 0; r < 16; ++r) {
            uint32_t v = best[r];
            #pragma unroll
            for (int off = 1; off < 32; off <<= 1) {
                uint32_t ov = (uint32_t)__shfl_xor((int)v, off);
                if (ov < v) v = ov;
            }
            best[r] = v;
        }
        if (l32 == 0) {
            #pragma unroll
            for (int r = 0; r < 16; ++r) {
                int row = wm * 32 + (r & 3) + 8 * (r >> 2) + 4 * half;
                mslot[wn * 64 + row] = best[r];
            }
        }
        asm volatile("s_waitcnt lgkmcnt(0)" ::: "memory");
        __builtin_amdgcn_s_barrier();
        if (t < 64) {
            uint32_t s0 = mslot[t], s1 = mslot[64 + t];
            uint32_t s2 = mslot[128 + t], s3 = mslot[192 + t];
            uint32_t s = s0 < s1 ? s0 : s1;
            if (s2 < s) s = s2;
            if (s3 < s) s = s3;
            codes[t] = (int)(s & 1023u);
            bvacc += __uint_as_float(s & 0xFFFFFC00u);   // 1 + wnorm[code] - 2*dot
        }
        asm volatile("s_waitcnt lgkmcnt(0)" ::: "memory");
        __builtin_amdgcn_s_barrier();
    };

    auto gather_half = [&](float* outp) { // 8 loads + 8 stores per wave (G = 16 vmem ops)
        f32x4* oblk = (f32x4*)outp;
        f32x4 gv[8];
        #pragma unroll
        for (int j = 0; j < 8; ++j) {
            int row = j * 8 + wave;      // wave-uniform
            int code = __builtin_amdgcn_readfirstlane(codes[row]);
            gv[j] = ((const f32x4*)(W + (size_t)code * FEATURES))[lane];
        }
        #pragma unroll
        for (int j = 0; j < 8; ++j)
            oblk[j * THREADS + t] = gv[j];
    };

// one K step: 8 MFMA from buf S%3, counted wait, raw barrier, prefetch((S+3)&15 -> S%3),
// optional h1 x-burst (XA) / pack iteration (PK). LG=1 adds lgkmcnt(0) (publish A(h1)).
#define K_STEP(S, WN, LG, DOPF, XA, PK)                                                   \
    {                                                                                     \
        const char* buf_ = bufs + ((S) % 3) * TILE_BYTES;                                 \
        __builtin_amdgcn_s_setprio(1);                                                    \
        _Pragma("unroll")                                                                 \
        for (int s2 = 0; s2 < 8; ++s2) {                                                  \
            int u = s2 * 2 + half;                                                        \
            long b0 = *(const long*)(buf_ + n0 * 128 + ((u ^ (n0 & 15)) * 8));            \
            acc = __builtin_amdgcn_mfma_f32_32x32x16_fp8_fp8(af[((S) & 1) * 8 + s2], b0, acc, 0, 0, 0); \
        }                                                                                 \
        __builtin_amdgcn_s_setprio(0);                                                    \
        if (LG) asm volatile("s_waitcnt vmcnt(" #WN ") lgkmcnt(0)" ::: "memory");         \
        else    asm volatile("s_waitcnt vmcnt(" #WN ")" ::: "memory");                    \
        __builtin_amdgcn_s_barrier();                                                     \
        if (DOPF) prefetch(((S) + 3) & 15, (S) % 3);                                      \
        if ((XA) >= 0) {                                                                  \
            _Pragma("unroll")                                                             \
            for (int j = 0; j < 4; ++j) xc[j] = xb1[((XA) * 4 + j) * THREADS + t];        \
        }                                                                                 \
        if ((PK) >= 0) ssacc += pack_one((PK), xc[(PK) & 3]);                             \
    }

    // ---- K(h0): steps 0..15; x(h1) bursts at 0,6; packs at 2..5,7..10 ----
    { f32x16 acc = {}; K_STEP(0, 63, 0, 1, 0, -1) K_STEP(1, 63, 0, 1, -1, -1) epi(0, acc); }
    { f32x16 acc = {}; K_STEP(2,  6, 0, 1, -1, 0) K_STEP(3,  2, 0, 1, -1, 1) epi(1, acc); }
    { f32x16 acc = {}; K_STEP(4,  2, 0, 1, -1, 2) K_STEP(5,  2, 0, 1, -1, 3) epi(2, acc); }
    { f32x16 acc = {}; K_STEP(6,  2, 0, 1, 1, -1) K_STEP(7,  6, 0, 1, -1, 4) epi(3, acc); }
    { f32x16 acc = {}; K_STEP(8,  6, 0, 1, -1, 5) K_STEP(9,  2, 0, 1, -1, 6) epi(4, acc); }
    { f32x16 acc = {}; K_STEP(10, 2, 0, 1, -1, 7) K_STEP(11, 2, 0, 1, -1, -1) epi(5, acc); }
    { f32x16 acc = {}; K_STEP(12, 2, 0, 1, -1, -1) K_STEP(13, 2, 0, 1, -1, -1) epi(6, acc); }
    { f32x16 acc = {}; K_STEP(14, 2, 0, 1, -1, -1) K_STEP(15, 2, 1, 1, -1, -1) epi(7, acc); }

    // ---- inter-half: af(h1) (A published by S15's lgkm+bar), merge+gather(h0) ----
    extract_af();
    merge_half();
    gather_half(out + (size_t)m0 * FEATURES);    // 16 vmem ops drain under K(h1)
    #pragma unroll
    for (int j = 0; j < 16; ++j) best[j] = 0xFFFFFFFFu;

    // ---- K(h1): steps 16..31 (B tiles recycle; pf continues through step 28) ----
    { f32x16 acc = {}; K_STEP(16, 18, 0, 1, -1, -1) K_STEP(17, 18, 0, 1, -1, -1) epi(0, acc); }
    { f32x16 acc = {}; K_STEP(18,  2, 0, 1, -1, -1) K_STEP(19,  2, 0, 1, -1, -1) epi(1, acc); }
    { f32x16 acc = {}; K_STEP(20,  2, 0, 1, -1, -1) K_STEP(21,  2, 0, 1, -1, -1) epi(2, acc); }
    { f32x16 acc = {}; K_STEP(22,  2, 0, 1, -1, -1) K_STEP(23,  2, 0, 1, -1, -1) epi(3, acc); }
    { f32x16 acc = {}; K_STEP(24,  2, 0, 1, -1, -1) K_STEP(25,  2, 0, 1, -1, -1) epi(4, acc); }
    { f32x16 acc = {}; K_STEP(26,  2, 0, 1, -1, -1) K_STEP(27,  2, 0, 1, -1, -1) epi(5, acc); }
    { f32x16 acc = {}; K_STEP(28,  2, 0, 1, -1, -1) K_STEP(29,  2, 0, 0, -1, -1) epi(6, acc); }
    { f32x16 acc = {}; K_STEP(30,  0, 0, 0, -1, -1) K_STEP(31, 63, 0, 0, -1, -1) epi(7, acc); }
#undef K_STEP

    merge_half();
    gather_half(out + (size_t)(m0 + 64) * FEATURES);

    // ---- deviation: bv over both halves (t<64) + ss over both stages ----
    {
        float ssw = ssacc;
        #pragma unroll
        for (int off = 32; off > 0; off >>= 1) ssw += __shfl_xor(ssw, off);
        if (lane == 0) sspart[wave] = ssw;
        asm volatile("s_waitcnt lgkmcnt(0)" ::: "memory");
        __builtin_amdgcn_s_barrier();
        if (t < 64) {
            float bv = bvacc;
            #pragma unroll
            for (int off = 32; off > 0; off >>= 1) bv += __shfl_xor(bv, off);
            if (t == 0) {
                float sst = 0.f;
                #pragma unroll
                for (int w = 0; w < 8; ++w) sst += sspart[w];
                atomicAdd(devslot, scale * (bv - 128.0f + sst));  // un-bias: -1/pixel
            }
        }
    }
}

extern "C" void kernel_launch(void* const* d_in, const int* in_sizes, int n_in,
                              void* d_out, int out_size, void* d_ws, size_t ws_size,
                              hipStream_t stream) {
    const float* x = (const float*)d_in[0];
    const float* W = (const float*)d_in[1];
    float* out = (float*)d_out;

    char*  Wt    = (char*)d_ws;                                   // 256 KB fp8 tiles
    float* wnorm = (float*)((char*)d_ws + 16 * TILE_BYTES);       // 4 KB
    float* devslot = out + (size_t)NPIX * FEATURES;               // d_out tail

    hipFuncSetAttribute(reinterpret_cast<const void*>(vq_main),
                        hipFuncAttributeMaxDynamicSharedMemorySize, SMEM_BYTES);

    vq_prep<<<SYMBOLS, 64, 0, stream>>>(W, Wt, wnorm, devslot);
    vq_main<<<NPIX / M_TILE, THREADS, SMEM_BYTES, stream>>>(x, W, Wt, wnorm, out, devslot);
}

// Round 8
// 153.359 us; speedup vs baseline: 1.4610x; 1.4610x over previous
//
#include <hip/hip_runtime.h>
#include <hip/hip_bf16.h>
#include <stdint.h>

#define FEATURES 256
#define SYMBOLS  1024
#define NPIX     65536        // 16*64*64
#define M_TILE   128
#define THREADS  512          // 8 waves: wm = wave>>1 (32-row band), wn = wave&1 (64-col half)
#define A_BYTES  32768        // A image: 128 rows x 256 B fp8 (stage only; becomes B-buffers 2,3)
#define TILE_BYTES 16384      // B tile: 128 syms x 128 feats fp8, pre-swizzled DMA image
#define EXTRA_BYTES 6144      // mslot[256](1K) + codes[128](512B) + sspart(32B) + wlds[1024](4K)
#define SMEM_BYTES (A_BYTES + 2 * TILE_BYTES + EXTRA_BYTES)   // 70 KB -> 2 blocks/CU

typedef float f32x4  __attribute__((ext_vector_type(4)));
typedef float f32x16 __attribute__((ext_vector_type(16)));

// async global->LDS DMA, 16 B per lane; LDS dest = uniform base + lane*16
__device__ __forceinline__ void gld_lds16(const void* g, void* l) {
    __builtin_amdgcn_global_load_lds(
        (const __attribute__((address_space(1))) unsigned int*)g,
        (__attribute__((address_space(3))) unsigned int*)l, 16, 0, 0);
}

// pack 4 fp32 -> 4 fp8 e4m3 (OCP), byte j = element j   [validated: absmax 1.95e-3]
__device__ __forceinline__ uint32_t pack_fp8x4(float a, float b, float c, float d) {
    uint32_t u = 0;
    u = __builtin_amdgcn_cvt_pk_fp8_f32(a, b, u, false);
    u = __builtin_amdgcn_cvt_pk_fp8_f32(c, d, u, true);
    return u;
}

// ---- prep: fp8 DMA-image codebook (x256 scale keeps e4m3 normal), wnorm+1 bias, dev=0 ----
// wnorm stores 1.0 + ||w||^2 so main-kernel scores are strictly positive: float bits are
// then directly monotone as uint. Deviation un-biases by subtracting 1.0 per pixel.
// Tile tt=nc*2+kt: syms [nc*128,+128) x feats [kt*128,+128). Row n = 128 B = 16 8-B
// units; unit u (feats kt*128 + (u>>1)*16 + (u&1)*8 ..+8) stored at phys u^(n&15).
__global__ __launch_bounds__(64) void vq_prep(const float* __restrict__ W,
                                              char* __restrict__ Wt,
                                              float* __restrict__ wnorm,
                                              float* __restrict__ devslot) {
    int s = blockIdx.x;
    int lane = threadIdx.x;
    int n  = s & 127;
    int nc = s >> 7;
    f32x4 v = ((const f32x4*)(W + (size_t)s * FEATURES))[lane];
    float ss = v[0]*v[0] + v[1]*v[1] + v[2]*v[2] + v[3]*v[3];
    #pragma unroll
    for (int off = 32; off > 0; off >>= 1) ss += __shfl_xor(ss, off);
    if (lane == 0) wnorm[s] = ss + 1.0f;          // +1 bias: keys strictly positive
    if (s == 0 && lane == 0) *devslot = 0.f;

    if (lane < 32) {
        int kt = lane >> 4;          // 0..1
        int u  = lane & 15;          // 8-B unit within the 128-B tile row
        const float* src = W + (size_t)s * FEATURES + kt * 128 + (u >> 1) * 16 + (u & 1) * 8;
        uint32_t a = pack_fp8x4(256.f*src[0], 256.f*src[1], 256.f*src[2], 256.f*src[3]);
        uint32_t b = pack_fp8x4(256.f*src[4], 256.f*src[5], 256.f*src[6], 256.f*src[7]);
        uint2 w2 = {a, b};
        *(uint2*)(Wt + (size_t)(nc * 2 + kt) * TILE_BYTES + n * 128 + ((u ^ (n & 15)) * 8)) = w2;
    }
}

// ---- main: 32x32x16 fp8, A-stationary, 4-deep DMA B, ONE barrier per nc (2 tiles) ----
// Buffer map: tile tt lives at smem + ((tt+2)&3)*16K (tiles 0,1 -> 32K/48K so they can
// prefetch during stage; tiles 2,3 -> the dead A-image region after af extraction).
// Per nc: compute tiles 2nc,2nc+1 -> epi -> s_waitcnt vmcnt(0) -> s_barrier ->
// pf(2nc+4), pf(2nc+5). Safety: bar(nc) proves all waves read 2nc,2nc+1 (so their bufs
// may be overwritten), and vmcnt(0) there drains pf(2nc+2,+3) (issued one nc ~4k cycles
// earlier -> the drain is nearly free). 8 barriers instead of 17; no counted-vmcnt tables.
// x loads / out stores carry nontemporal hints to keep Wt/W L2-resident.
__global__ __launch_bounds__(THREADS)
__attribute__((amdgpu_waves_per_eu(4, 4)))   // pin 4 waves/EU: reg budget 128, 2 blocks/CU
void vq_main(
        const float*  __restrict__ x,
        const float*  __restrict__ W,
        const char*   __restrict__ Wt,
        const float*  __restrict__ wnorm,
        float*        __restrict__ out,
        float*        __restrict__ devslot) {
    extern __shared__ char smem[];
    const int t    = threadIdx.x;
    const int lane = t & 63;
    const int wave = t >> 6;             // 0..7
    const int l32  = lane & 31;
    const int half = lane >> 5;          // k-half within a 16-K step
    const int wm   = wave >> 1;          // 0..3: 32-pixel-row band
    const int wn   = wave & 1;           // 0..1: 64-symbol-col half
    const int m0   = blockIdx.x * M_TILE;
    const float scale = 1.25f / ((float)NPIX * (float)FEATURES);

    uint32_t* mslot = (uint32_t*)(smem + A_BYTES + 2 * TILE_BYTES);          // [2][128]
    int*      codes = (int*)(smem + A_BYTES + 2 * TILE_BYTES + 1024);        // [128]
    float*    sspart = (float*)(smem + A_BYTES + 2 * TILE_BYTES + 1536);     // [8]
    float*    wlds  = (float*)(smem + A_BYTES + 2 * TILE_BYTES + 2048);      // [1024]

    auto prefetch = [&](int tt) {        // lane-linear: tile tt is contiguous 16 KB
        const char* g = Wt + (size_t)tt * TILE_BYTES;
        char* dst = smem + (((tt + 2) & 3) * TILE_BYTES);
        #pragma unroll
        for (int j = 0; j < 2; ++j) {
            int i = wave * 2 + j;        // 16 instrs x 1 KB
            gld_lds16(g + i * 1024 + lane * 16, dst + i * 1024);
        }
    };

    prefetch(0);                         // flies under the stage-A global loads
    prefetch(1);

    // ---- Stage A: x fp32 -> fp8 image; row r = 256 B = 32 8-B units, phys = u^(r&31) ----
    // All 16 f32x4 loads issued up front (nontemporal: x is streamed once).
    const f32x4* xblk = (const f32x4*)(x + (size_t)m0 * FEATURES);
    f32x4 xv[16];
    #pragma unroll
    for (int i = 0; i < 16; ++i) xv[i] = __builtin_nontemporal_load(xblk + i * THREADS + t);
    wlds[t] = wnorm[t];                  // LDS copy of wnorm: keeps the K-loop vmem stream clean
    wlds[t + 512] = wnorm[t + 512];
    float ss = 0.f;
    #pragma unroll
    for (int i = 0; i < 16; ++i) {
        int idx = i * THREADS + t;       // 8192 float4
        int row = idx >> 6;              // wave-uniform
        int k4  = idx & 63;
        f32x4 v = xv[i];
        ss += v[0]*v[0] + v[1]*v[1] + v[2]*v[2] + v[3]*v[3];
        uint32_t pk = pack_fp8x4(v[0], v[1], v[2], v[3]);
        int u = k4 >> 1;                 // unit 0..31
        *(uint32_t*)(smem + row * 256 + ((u ^ (row & 31)) * 8) + (k4 & 1) * 4) = pk;
    }
    #pragma unroll
    for (int off = 32; off > 0; off >>= 1) ss += __shfl_xor(ss, off);
    if (lane == 0) sspart[wave] = ss;
    __syncthreads();                     // A visible; DMA(0),(1) + x/wnorm loads drained

    // ---- A-stationary: af[s] = 8 fp8 for kstep s (k = s*16 + half*8 ..+8), 32 regs ----
    long af[16];
    {
        int r = wm * 32 + l32;           // pixel row (r&31 == l32)
        #pragma unroll
        for (int s = 0; s < 16; ++s)
            af[s] = *(const long*)(smem + r * 256 + (((s * 2 + half) ^ l32) * 8));
    }
    __syncthreads();                     // A-image dead for ALL waves -> region becomes bufs 2,3
    prefetch(2);
    prefetch(3);

    uint32_t best[16];
    #pragma unroll
    for (int j = 0; j < 16; ++j) best[j] = 0xFFFFFFFFu;

    const int n0 = wn * 64 + l32;        // tile-local B rows for this lane
    const int n1 = wn * 64 + 32 + l32;

    #pragma unroll 1
    for (int nc = 0; nc < 8; ++nc) {
        int nb0 = nc * 128 + wn * 64 + l32;
        float w0 = wlds[nb0 & 1023], w1 = wlds[(nb0 + 32) & 1023];
        f32x16 acc0 = {}, acc1 = {};
        #pragma unroll
        for (int kt = 0; kt < 2; ++kt) {
            const int tt = nc * 2 + kt;
            const char* buf = smem + (((tt + 2) & 3) * TILE_BYTES);
            __builtin_amdgcn_s_setprio(1);
            #pragma unroll
            for (int s2 = 0; s2 < 8; ++s2) {   // interleaved ds_read->MFMA (compiler pipelines)
                int u = s2 * 2 + half;
                long b0 = *(const long*)(buf + n0 * 128 + ((u ^ (n0 & 15)) * 8));
                long b1 = *(const long*)(buf + n1 * 128 + ((u ^ (n1 & 15)) * 8));
                acc0 = __builtin_amdgcn_mfma_f32_32x32x16_fp8_fp8(af[kt*8+s2], b0, acc0, 0, 0, 0);
                acc1 = __builtin_amdgcn_mfma_f32_32x32x16_fp8_fp8(af[kt*8+s2], b1, acc1, 0, 0, 0);
            }
            __builtin_amdgcn_s_setprio(0);
        }
        // epilogue: score = (1 + wnorm) - (2/256)*acc > 0 -> float bits monotone as uint
        #pragma unroll
        for (int r = 0; r < 16; ++r) {
            float v0 = __builtin_fmaf(-0.0078125f, acc0[r], w0);
            float v1 = __builtin_fmaf(-0.0078125f, acc1[r], w1);
            uint32_t k0 = (__float_as_uint(v0) & 0xFFFFFC00u) | (uint32_t)nb0;
            uint32_t k1 = (__float_as_uint(v1) & 0xFFFFFC00u) | (uint32_t)(nb0 + 32);
            uint32_t m  = k0 < k1 ? k0 : k1;
            best[r] = best[r] < m ? best[r] : m;
        }
        if (nc < 7) {
            asm volatile("s_waitcnt vmcnt(0)" ::: "memory");   // drains pf issued one nc ago: ~free
            __builtin_amdgcn_s_barrier();                      // publish next pair; bufs of this pair free
            if (nc < 6) { prefetch(nc * 2 + 4); prefetch(nc * 2 + 5); }
        }
    }

    // cross-lane merge within each 32-lane group (cols of this lane's rows)
    #pragma unroll
    for (int r = 0; r < 16; ++r) {
        uint32_t v = best[r];
        #pragma unroll
        for (int off = 1; off < 32; off <<= 1) {
            uint32_t ov = (uint32_t)__shfl_xor((int)v, off);
            if (ov < v) v = ov;
        }
        best[r] = v;
    }
    if (l32 == 0) {                      // lanes 0 and 32: rows differ by 4*half
        #pragma unroll
        for (int r = 0; r < 16; ++r) {
            int row = wm * 32 + (r & 3) + 8 * (r >> 2) + 4 * half;
            mslot[wn * 128 + row] = best[r];
        }
    }
    __syncthreads();

    if (t < 128) {                       // merge wn halves; deviation partials
        uint32_t s0 = mslot[t], s1 = mslot[128 + t];
        uint32_t s = (s1 < s0) ? s1 : s0;
        codes[t] = (int)(s & 1023u);
        float bv = __uint_as_float(s & 0xFFFFFC00u);  // = 1 + wnorm[code] - 2*best_dot (quantized)
        #pragma unroll
        for (int off = 32; off > 0; off >>= 1) bv += __shfl_xor(bv, off);
        if (lane == 0) atomicAdd(devslot, scale * (bv - 64.0f));  // un-bias: -1 per pixel
        if (t == 0) {
            float sst = 0.f;
            #pragma unroll
            for (int w = 0; w < 8; ++w) sst += sspart[w];
            atomicAdd(devslot, scale * sst);
        }
    }
    __syncthreads();

    // ---- out = W[code] (exact fp32 gather from the original codebook) ----
    // two 8-deep batches; nontemporal stores (out is written once, keep L2 for Wt/W)
    f32x4* oblk = (f32x4*)(out + (size_t)m0 * FEATURES);
    #pragma unroll
    for (int h = 0; h < 2; ++h) {
        f32x4 g[8];
        #pragma unroll
        for (int j = 0; j < 8; ++j) {
            int idx = (h * 8 + j) * THREADS + t;
            int row = idx >> 6;          // wave-uniform
            int code = __builtin_amdgcn_readfirstlane(codes[row]);
            g[j] = ((const f32x4*)(W + (size_t)code * FEATURES))[idx & 63];
        }
        #pragma unroll
        for (int j = 0; j < 8; ++j)
            __builtin_nontemporal_store(g[j], oblk + (h * 8 + j) * THREADS + t);
    }
}

extern "C" void kernel_launch(void* const* d_in, const int* in_sizes, int n_in,
                              void* d_out, int out_size, void* d_ws, size_t ws_size,
                              hipStream_t stream) {
    const float* x = (const float*)d_in[0];
    const float* W = (const float*)d_in[1];
    float* out = (float*)d_out;

    char*  Wt    = (char*)d_ws;                                   // 256 KB fp8 tiles
    float* wnorm = (float*)((char*)d_ws + 16 * TILE_BYTES);       // 4 KB
    float* devslot = out + (size_t)NPIX * FEATURES;               // d_out tail

    hipFuncSetAttribute(reinterpret_cast<const void*>(vq_main),
                        hipFuncAttributeMaxDynamicSharedMemorySize, SMEM_BYTES);

    vq_prep<<<SYMBOLS, 64, 0, stream>>>(W, Wt, wnorm, devslot);
    vq_main<<<NPIX / M_TILE, THREADS, SMEM_BYTES, stream>>>(x, W, Wt, wnorm, out, devslot);
}

// Round 9
// 151.839 us; speedup vs baseline: 1.4756x; 1.0100x over previous
//
#include <hip/hip_runtime.h>
#include <hip/hip_bf16.h>
#include <stdint.h>

#define FEATURES 256
#define SYMBOLS  1024
#define NPIX     65536        // 16*64*64
#define M_TILE   128
#define THREADS  512          // 8 waves: wm = wave>>1 (32-row band), wn = wave&1 (64-col half)
#define A_BYTES  32768        // A image: 128 rows x 256 B fp8 (stage only; becomes B-buffers 2,3)
#define TILE_BYTES 16384      // B tile: 128 syms x 128 feats fp8, pre-swizzled DMA image
#define EXTRA_BYTES 6144      // mslot[256](1K) + codes[128](512B) + sspart(32B) + wlds[1024](4K)
#define SMEM_BYTES (A_BYTES + 2 * TILE_BYTES + EXTRA_BYTES)   // 70 KB -> 2 blocks/CU

typedef float f32x4  __attribute__((ext_vector_type(4)));
typedef float f32x16 __attribute__((ext_vector_type(16)));
typedef int   i32x8  __attribute__((ext_vector_type(8)));

// async global->LDS DMA, 16 B per lane; LDS dest = uniform base + lane*16
__device__ __forceinline__ void gld_lds16(const void* g, void* l) {
    __builtin_amdgcn_global_load_lds(
        (const __attribute__((address_space(1))) unsigned int*)g,
        (__attribute__((address_space(3))) unsigned int*)l, 16, 0, 0);
}

// pack 4 fp32 -> 4 fp8 e4m3 (OCP), byte j = element j   [validated: absmax 1.95e-3]
__device__ __forceinline__ uint32_t pack_fp8x4(float a, float b, float c, float d) {
    uint32_t u = 0;
    u = __builtin_amdgcn_cvt_pk_fp8_f32(a, b, u, false);
    u = __builtin_amdgcn_cvt_pk_fp8_f32(c, d, u, true);
    return u;
}

// ---- prep: fp8 DMA-image codebook (x256 scale keeps e4m3 normal), wnorm+1 bias, dev=0 ----
// wnorm stores 1.0 + ||w||^2 so main-kernel scores are strictly positive: float bits are
// then directly monotone as uint. Deviation un-biases by subtracting 1.0 per pixel.
// Tile tt=nc*2+kt: syms [nc*128,+128) x feats [kt*128,+128). Row n = 128 B = 16 8-B
// units; unit u (feats kt*128 + (u>>1)*16 + (u&1)*8 ..+8) stored at phys u^(n&15).
__global__ __launch_bounds__(64) void vq_prep(const float* __restrict__ W,
                                              char* __restrict__ Wt,
                                              float* __restrict__ wnorm,
                                              float* __restrict__ devslot) {
    int s = blockIdx.x;
    int lane = threadIdx.x;
    int n  = s & 127;
    int nc = s >> 7;
    f32x4 v = ((const f32x4*)(W + (size_t)s * FEATURES))[lane];
    float ss = v[0]*v[0] + v[1]*v[1] + v[2]*v[2] + v[3]*v[3];
    #pragma unroll
    for (int off = 32; off > 0; off >>= 1) ss += __shfl_xor(ss, off);
    if (lane == 0) wnorm[s] = ss + 1.0f;          // +1 bias: keys strictly positive
    if (s == 0 && lane == 0) *devslot = 0.f;

    if (lane < 32) {
        int kt = lane >> 4;          // 0..1
        int u  = lane & 15;          // 8-B unit within the 128-B tile row
        const float* src = W + (size_t)s * FEATURES + kt * 128 + (u >> 1) * 16 + (u & 1) * 8;
        uint32_t a = pack_fp8x4(256.f*src[0], 256.f*src[1], 256.f*src[2], 256.f*src[3]);
        uint32_t b = pack_fp8x4(256.f*src[4], 256.f*src[5], 256.f*src[6], 256.f*src[7]);
        uint2 w2 = {a, b};
        *(uint2*)(Wt + (size_t)(nc * 2 + kt) * TILE_BYTES + n * 128 + ((u ^ (n & 15)) * 8)) = w2;
    }
}

// ---- main: MX-scaled 32x32x64 fp8 (scale=1.0), A-stationary, R4's 4-deep DMA schedule ----
// Identical to the verified R4 kernel except the K-computation: 4x fewer MFMA instrs at
// 2.1x the rate (4686 vs 2190 TF measured). Lane k-mapping for 32x32x64: row/col = l&31,
// k = (l>>5)*32 + byte -> operand o (k in [64o,64o+64)) needs feat-units 8o+4*half+j,
// j=0..3 (both parities -> extraction indices differ from the 16-K-step form; re-derived).
// Scales = 0x7F (e8m0 2^0 = 1.0) -> math identical to the non-scaled fp8 path.
__global__ __launch_bounds__(THREADS)
__attribute__((amdgpu_waves_per_eu(4, 4)))   // pin 4 waves/EU: reg budget 128, 2 blocks/CU
void vq_main(
        const float*  __restrict__ x,
        const float*  __restrict__ W,
        const char*   __restrict__ Wt,
        const float*  __restrict__ wnorm,
        float*        __restrict__ out,
        float*        __restrict__ devslot) {
    extern __shared__ char smem[];
    const int t    = threadIdx.x;
    const int lane = t & 63;
    const int wave = t >> 6;             // 0..7
    const int l32  = lane & 31;
    const int half = lane >> 5;          // k-half selector: this lane covers k = 32*half..+32 per op
    const int wm   = wave >> 1;          // 0..3: 32-pixel-row band
    const int wn   = wave & 1;           // 0..1: 64-symbol-col half
    const int m0   = blockIdx.x * M_TILE;
    const float scale = 1.25f / ((float)NPIX * (float)FEATURES);

    uint32_t* mslot = (uint32_t*)(smem + A_BYTES + 2 * TILE_BYTES);          // [2][128]
    int*      codes = (int*)(smem + A_BYTES + 2 * TILE_BYTES + 1024);        // [128]
    float*    sspart = (float*)(smem + A_BYTES + 2 * TILE_BYTES + 1536);     // [8]
    float*    wlds  = (float*)(smem + A_BYTES + 2 * TILE_BYTES + 2048);      // [1024]

    auto prefetch = [&](int tt) {        // lane-linear: tile tt is contiguous 16 KB
        const char* g = Wt + (size_t)tt * TILE_BYTES;
        char* dst = smem + (((tt + 2) & 3) * TILE_BYTES);
        #pragma unroll
        for (int j = 0; j < 2; ++j) {
            int i = wave * 2 + j;        // 16 instrs x 1 KB
            gld_lds16(g + i * 1024 + lane * 16, dst + i * 1024);
        }
    };

    prefetch(0);                         // flies under the stage-A global loads
    prefetch(1);

    // ---- Stage A: x fp32 -> fp8 image; row r = 256 B = 32 8-B units, phys = u^(r&31) ----
    const f32x4* xblk = (const f32x4*)(x + (size_t)m0 * FEATURES);
    f32x4 xv[16];
    #pragma unroll
    for (int i = 0; i < 16; ++i) xv[i] = xblk[i * THREADS + t];
    wlds[t] = wnorm[t];                  // LDS copy of wnorm: keeps the K-loop vmcnt clean
    wlds[t + 512] = wnorm[t + 512];
    float ss = 0.f;
    #pragma unroll
    for (int i = 0; i < 16; ++i) {
        int idx = i * THREADS + t;       // 8192 float4
        int row = idx >> 6;              // wave-uniform
        int k4  = idx & 63;
        f32x4 v = xv[i];
        ss += v[0]*v[0] + v[1]*v[1] + v[2]*v[2] + v[3]*v[3];
        uint32_t pk = pack_fp8x4(v[0], v[1], v[2], v[3]);
        int u = k4 >> 1;                 // unit 0..31
        *(uint32_t*)(smem + row * 256 + ((u ^ (row & 31)) * 8) + (k4 & 1) * 4) = pk;
    }
    #pragma unroll
    for (int off = 32; off > 0; off >>= 1) ss += __shfl_xor(ss, off);
    if (lane == 0) sspart[wave] = ss;
    __syncthreads();                     // A visible; DMA(0),(1) + x/wnorm loads drained

    // ---- A-stationary: Aop[o] = 32 fp8 for k = 64o + 32*half .. +32 (units 8o+4h+j) ----
    i32x8 Aop[4];                        // 32 VGPRs, same budget as the old af[16]
    {
        int r = wm * 32 + l32;           // pixel row (r&31 == l32)
        #pragma unroll
        for (int o = 0; o < 4; ++o) {
            #pragma unroll
            for (int j = 0; j < 4; ++j) {
                long v = *(const long*)(smem + r * 256 + (((o * 8 + half * 4 + j) ^ l32) * 8));
                Aop[o][j * 2]     = (int)(uint32_t)((unsigned long)v);
                Aop[o][j * 2 + 1] = (int)(uint32_t)((unsigned long)v >> 32);
            }
        }
    }
    __syncthreads();                     // A-image dead for ALL waves -> region becomes bufs 2,3
    prefetch(2);
    prefetch(3);

    uint32_t best[16];
    #pragma unroll
    for (int j = 0; j < 16; ++j) best[j] = 0xFFFFFFFFu;

    const int n0 = wn * 64 + l32;        // tile-local B rows for this lane
    const int n1 = wn * 64 + 32 + l32;

// one K-tile: 16 ds_read_b64 + 4 MFMA-scale (K=64 each), then counted-vmcnt wait for
// tile TT+1 (own share), raw barrier (publish), prefetch TT+4. Schedule = R4's, verified.
#define TILE_STEP(TT, WN, BAR, PF)                                                        \
    {                                                                                     \
        const int tt_ = (TT);                                                             \
        const char* buf = smem + (((tt_ + 2) & 3) * TILE_BYTES);                          \
        const int kt_ = tt_ & 1;                                                          \
        __builtin_amdgcn_s_setprio(1);                                                    \
        _Pragma("unroll")                                                                 \
        for (int o = 0; o < 2; ++o) {                                                     \
            long t0[4], t1[4];                                                            \
            _Pragma("unroll")                                                             \
            for (int j = 0; j < 4; ++j) {                                                 \
                int u = o * 8 + half * 4 + j;                                             \
                t0[j] = *(const long*)(buf + n0 * 128 + ((u ^ (n0 & 15)) * 8));           \
                t1[j] = *(const long*)(buf + n1 * 128 + ((u ^ (n1 & 15)) * 8));           \
            }                                                                             \
            i32x8 B0, B1;                                                                 \
            _Pragma("unroll")                                                             \
            for (int j = 0; j < 4; ++j) {                                                 \
                B0[j * 2]     = (int)(uint32_t)((unsigned long)t0[j]);                    \
                B0[j * 2 + 1] = (int)(uint32_t)((unsigned long)t0[j] >> 32);              \
                B1[j * 2]     = (int)(uint32_t)((unsigned long)t1[j]);                    \
                B1[j * 2 + 1] = (int)(uint32_t)((unsigned long)t1[j] >> 32);              \
            }                                                                             \
            acc0 = __builtin_amdgcn_mfma_scale_f32_32x32x64_f8f6f4(                       \
                       Aop[kt_ * 2 + o], B0, acc0, 0, 0, 0, 0x7F7F7F7F, 0, 0x7F7F7F7F);   \
            acc1 = __builtin_amdgcn_mfma_scale_f32_32x32x64_f8f6f4(                       \
                       Aop[kt_ * 2 + o], B1, acc1, 0, 0, 0, 0x7F7F7F7F, 0, 0x7F7F7F7F);   \
        }                                                                                 \
        __builtin_amdgcn_s_setprio(0);                                                    \
        asm volatile("s_waitcnt vmcnt(" #WN ")" ::: "memory");                            \
        if (BAR) __builtin_amdgcn_s_barrier();                                            \
        if (PF) prefetch(tt_ + 4);                                                        \
    }

    auto epi = [&](int nc, const f32x16& acc0, const f32x16& acc1) {
        // score = (1 + wnorm) - (2/256)*acc > 0 -> float bits monotone as uint
        int nb0 = nc * 128 + wn * 64 + l32;
        float w0 = wlds[nb0 & 1023], w1 = wlds[(nb0 + 32) & 1023];
        #pragma unroll
        for (int r = 0; r < 16; ++r) {
            float v0 = __builtin_fmaf(-0.0078125f, acc0[r], w0);
            float v1 = __builtin_fmaf(-0.0078125f, acc1[r], w1);
            uint32_t k0 = (__float_as_uint(v0) & 0xFFFFFC00u) | (uint32_t)nb0;
            uint32_t k1 = (__float_as_uint(v1) & 0xFFFFFC00u) | (uint32_t)(nb0 + 32);
            uint32_t m  = k0 < k1 ? k0 : k1;
            best[r] = best[r] < m ? best[r] : m;
        }
    };

    #pragma unroll 1
    for (int nc = 0; nc < 6; ++nc) {
        f32x16 acc0 = {}, acc1 = {};
        TILE_STEP(nc * 2,     4, 1, 1)
        TILE_STEP(nc * 2 + 1, 4, 1, 1)
        epi(nc, acc0, acc1);
    }
    {   // nc = 6: last prefetch was tile 15 (issued at tt=11); tail waits peel 4,2,0
        f32x16 acc0 = {}, acc1 = {};
        TILE_STEP(12, 4, 1, 0)
        TILE_STEP(13, 2, 1, 0)
        epi(6, acc0, acc1);
    }
    {   // nc = 7
        f32x16 acc0 = {}, acc1 = {};
        TILE_STEP(14, 0, 1, 0)
        TILE_STEP(15, 63, 0, 0)          // vmcnt(63) = no-op; nothing outstanding matters
        epi(7, acc0, acc1);
    }
#undef TILE_STEP

    // cross-lane merge within each 32-lane group (cols of this lane's rows)
    #pragma unroll
    for (int r = 0; r < 16; ++r) {
        uint32_t v = best[r];
        #pragma unroll
        for (int off = 1; off < 32; off <<= 1) {
            uint32_t ov = (uint32_t)__shfl_xor((int)v, off);
            if (ov < v) v = ov;
        }
        best[r] = v;
    }
    if (l32 == 0) {                      // lanes 0 and 32: rows differ by 4*half
        #pragma unroll
        for (int r = 0; r < 16; ++r) {
            int row = wm * 32 + (r & 3) + 8 * (r >> 2) + 4 * half;
            mslot[wn * 128 + row] = best[r];
        }
    }
    __syncthreads();

    if (t < 128) {                       // merge wn halves; deviation partials
        uint32_t s0 = mslot[t], s1 = mslot[128 + t];
        uint32_t s = (s1 < s0) ? s1 : s0;
        codes[t] = (int)(s & 1023u);
        float bv = __uint_as_float(s & 0xFFFFFC00u);  // = 1 + wnorm[code] - 2*best_dot (quantized)
        #pragma unroll
        for (int off = 32; off > 0; off >>= 1) bv += __shfl_xor(bv, off);
        if (lane == 0) atomicAdd(devslot, scale * (bv - 64.0f));  // un-bias: -1 per pixel
        if (t == 0) {
            float sst = 0.f;
            #pragma unroll
            for (int w = 0; w < 8; ++w) sst += sspart[w];
            atomicAdd(devslot, scale * sst);
        }
    }
    __syncthreads();

    // ---- out = W[code] (exact fp32 gather from the original codebook) ----
    // two 8-deep batches: 8 KB/wave of W reads in flight, stores fire-and-forget
    f32x4* oblk = (f32x4*)(out + (size_t)m0 * FEATURES);
    #pragma unroll
    for (int h = 0; h < 2; ++h) {
        f32x4 g[8];
        #pragma unroll
        for (int j = 0; j < 8; ++j) {
            int idx = (h * 8 + j) * THREADS + t;
            int row = idx >> 6;          // wave-uniform
            int code = __builtin_amdgcn_readfirstlane(codes[row]);
            g[j] = ((const f32x4*)(W + (size_t)code * FEATURES))[idx & 63];
        }
        #pragma unroll
        for (int j = 0; j < 8; ++j)
            oblk[(h * 8 + j) * THREADS + t] = g[j];
    }
}

extern "C" void kernel_launch(void* const* d_in, const int* in_sizes, int n_in,
                              void* d_out, int out_size, void* d_ws, size_t ws_size,
                              hipStream_t stream) {
    const float* x = (const float*)d_in[0];
    const float* W = (const float*)d_in[1];
    float* out = (float*)d_out;

    char*  Wt    = (char*)d_ws;                                   // 256 KB fp8 tiles
    float* wnorm = (float*)((char*)d_ws + 16 * TILE_BYTES);       // 4 KB
    float* devslot = out + (size_t)NPIX * FEATURES;               // d_out tail

    hipFuncSetAttribute(reinterpret_cast<const void*>(vq_main),
                        hipFuncAttributeMaxDynamicSharedMemorySize, SMEM_BYTES);

    vq_prep<<<SYMBOLS, 64, 0, stream>>>(W, Wt, wnorm, devslot);
    vq_main<<<NPIX / M_TILE, THREADS, SMEM_BYTES, stream>>>(x, W, Wt, wnorm, out, devslot);
}